// Round 1
// baseline (1473.750 us; speedup 1.0000x reference)
//
#include <hip/hip_runtime.h>

#define EPS 1e-5f
#define CHUNK 32

// ---------------- new_bxyz gather: out0[i] = point_bxyz[sample_idx[i]] ----------------
__global__ void gather_kernel(const float4* __restrict__ bxyz, const int* __restrict__ sidx,
                              float4* __restrict__ out, int M) {
    int i = blockIdx.x * blockDim.x + threadIdx.x;
    if (i < M) out[i] = bxyz[sidx[i]];
}

// ---------------- fused edge MLP (64->64) + segmented max into agg ----------------
// lane j owns output channel j (W0 column j in regs). edge_in element k lives in lane k,
// broadcast via readlane. e_new sorted -> run-length segmented max, atomic flush per run.
__global__ __launch_bounds__(256) void edge_kernel(
    const float* __restrict__ bxyz, const float* __restrict__ feat,
    const int* __restrict__ e_point, const int* __restrict__ e_new,
    const float* __restrict__ new_bxyz, const float* __restrict__ W0,
    const float* __restrict__ b0, float* __restrict__ agg, int E) {
    int lane = threadIdx.x & 63;
    int gwave = blockIdx.x * 4 + (threadIdx.x >> 6);
    int base = gwave * CHUNK;
    if (base >= E) return;
    int end = min(base + CHUNK, E);

    float w[64];
#pragma unroll
    for (int k = 0; k < 64; ++k) w[k] = W0[k * 64 + lane];
    float bias = b0[lane];

    float runmax = 0.f;   // == relu-identity: max(0, raw scores) == segment_max(relu(h))
    int curseg = -1;
    for (int e = base; e < end; ++e) {
        int p = e_point[e];
        int s = e_new[e];
        float x;
        if (lane < 3) x = bxyz[p * 4 + 1 + lane] - new_bxyz[s * 4 + 1 + lane];
        else          x = feat[p * 61 + (lane - 3)];
        int xi = __float_as_int(x);
        float a0 = 0.f, a1 = 0.f, a2 = 0.f, a3 = 0.f;
#pragma unroll
        for (int k = 0; k < 64; k += 4) {
            a0 = fmaf(__int_as_float(__builtin_amdgcn_readlane(xi, k + 0)), w[k + 0], a0);
            a1 = fmaf(__int_as_float(__builtin_amdgcn_readlane(xi, k + 1)), w[k + 1], a1);
            a2 = fmaf(__int_as_float(__builtin_amdgcn_readlane(xi, k + 2)), w[k + 2], a2);
            a3 = fmaf(__int_as_float(__builtin_amdgcn_readlane(xi, k + 3)), w[k + 3], a3);
        }
        float acc = ((a0 + a1) + (a2 + a3)) + bias;
        if (s != curseg) {
            if (curseg >= 0)
                atomicMax((int*)&agg[(size_t)curseg * 64 + lane], __float_as_int(runmax));
            curseg = s;
            runmax = 0.f;
        }
        runmax = fmaxf(runmax, acc);
    }
    if (curseg >= 0)
        atomicMax((int*)&agg[(size_t)curseg * 64 + lane], __float_as_int(runmax));
}

// ---------------- GEMM1: y1 = agg @ W1 (no bias; it cancels in BN) + moment partials ----------------
// tile 64 rows x 128 cols, 256 threads, thread = (col, row-half), acc[32].
__global__ __launch_bounds__(256) void gemm1_kernel(
    const float* __restrict__ agg, const float* __restrict__ W1,
    float* __restrict__ y1, float* __restrict__ p1sum, float* __restrict__ p1sq, int M) {
    __shared__ float As[64 * 64];
    __shared__ float Ws[64 * 128];
    __shared__ float ssum[256], ssq[256];
    int t = threadIdx.x;
    int row0 = blockIdx.x * 64;
#pragma unroll
    for (int j = 0; j < 4; ++j) {
        int idx4 = t + j * 256;
        int r = (idx4 * 4) >> 6;
        float4 v = make_float4(0.f, 0.f, 0.f, 0.f);
        if (row0 + r < M) v = ((const float4*)agg)[(size_t)row0 * 16 + idx4];
        ((float4*)As)[idx4] = v;
    }
#pragma unroll
    for (int j = 0; j < 8; ++j) {
        int idx4 = t + j * 256;
        ((float4*)Ws)[idx4] = ((const float4*)W1)[idx4];
    }
    __syncthreads();
    int c = t & 127;
    int rh = t >> 7;
    float acc[32];
#pragma unroll
    for (int rr = 0; rr < 32; ++rr) acc[rr] = 0.f;
    for (int k4 = 0; k4 < 16; ++k4) {
        float w0 = Ws[(k4 * 4 + 0) * 128 + c];
        float w1 = Ws[(k4 * 4 + 1) * 128 + c];
        float w2 = Ws[(k4 * 4 + 2) * 128 + c];
        float w3 = Ws[(k4 * 4 + 3) * 128 + c];
#pragma unroll
        for (int rr = 0; rr < 32; ++rr) {
            float4 a = *(const float4*)&As[(rh * 32 + rr) * 64 + k4 * 4];
            acc[rr] = fmaf(a.x, w0, acc[rr]);
            acc[rr] = fmaf(a.y, w1, acc[rr]);
            acc[rr] = fmaf(a.z, w2, acc[rr]);
            acc[rr] = fmaf(a.w, w3, acc[rr]);
        }
    }
    float s = 0.f, q = 0.f;
#pragma unroll
    for (int rr = 0; rr < 32; ++rr) {
        int r = row0 + rh * 32 + rr;
        if (r < M) y1[(size_t)r * 128 + c] = acc[rr];
        s += acc[rr];
        q += acc[rr] * acc[rr];   // padded rows contribute 0 to both moments
    }
    ssum[t] = s; ssq[t] = q;
    __syncthreads();
    if (t < 128) {
        p1sum[(size_t)blockIdx.x * 128 + t] = ssum[t] + ssum[t + 128];
        p1sq[(size_t)blockIdx.x * 128 + t]  = ssq[t] + ssq[t + 128];
    }
}

// ---------------- reduce moment partials -> per-channel BN scale/shift ----------------
__global__ void stats_kernel(const float* __restrict__ psum, const float* __restrict__ psq,
                             const float* __restrict__ g, const float* __restrict__ beta,
                             float* __restrict__ scale, float* __restrict__ shift,
                             int nblk, int ncols, float invM) {
    __shared__ float ss[256], qq[256];
    int c = blockIdx.x;
    int t = threadIdx.x;
    float s = 0.f, q = 0.f;
    for (int b = t; b < nblk; b += 256) {
        s += psum[(size_t)b * ncols + c];
        q += psq[(size_t)b * ncols + c];
    }
    ss[t] = s; qq[t] = q;
    __syncthreads();
    for (int off = 128; off > 0; off >>= 1) {
        if (t < off) { ss[t] += ss[t + off]; qq[t] += qq[t + off]; }
        __syncthreads();
    }
    if (t == 0) {
        float mean = ss[0] * invM;
        float var = qq[0] * invM - mean * mean;
        float sc = g[c] * rsqrtf(var + EPS);
        scale[c] = sc;
        shift[c] = beta[c] - mean * sc;
    }
}

// ---------------- GEMM2: y2 = bnrelu1(y1) @ W2, y2 written raw into d_out x-region ----------------
// tile 32 rows x 256 cols, K=128 in 4 LDS chunks; BN1+ReLU applied on X-tile load.
__global__ __launch_bounds__(256) void gemm2_kernel(
    const float* __restrict__ y1, const float* __restrict__ W2,
    const float* __restrict__ scale1, const float* __restrict__ shift1,
    float* __restrict__ yout, float* __restrict__ p2sum, float* __restrict__ p2sq, int M) {
    __shared__ float Xs[32 * 128];
    __shared__ float Ws[32 * 256];
    int t = threadIdx.x;
    int row0 = blockIdx.x * 32;
#pragma unroll
    for (int j = 0; j < 4; ++j) {
        int idx4 = t + j * 256;
        int flat = idx4 * 4;
        int r = flat >> 7;
        int c4 = (flat & 127) >> 2;
        float4 v = make_float4(0.f, 0.f, 0.f, 0.f);
        if (row0 + r < M) {
            float4 y = ((const float4*)y1)[(size_t)row0 * 32 + idx4];
            float4 sc = ((const float4*)scale1)[c4];
            float4 sh = ((const float4*)shift1)[c4];
            v.x = fmaxf(0.f, fmaf(y.x, sc.x, sh.x));
            v.y = fmaxf(0.f, fmaf(y.y, sc.y, sh.y));
            v.z = fmaxf(0.f, fmaf(y.z, sc.z, sh.z));
            v.w = fmaxf(0.f, fmaf(y.w, sc.w, sh.w));
        }
        ((float4*)Xs)[idx4] = v;
    }
    float acc[32];
#pragma unroll
    for (int rr = 0; rr < 32; ++rr) acc[rr] = 0.f;
    int c = t;
    for (int kc = 0; kc < 4; ++kc) {
        __syncthreads();   // Xs ready (kc=0) / previous Ws consumed
#pragma unroll
        for (int j = 0; j < 8; ++j) {
            int idx4 = t + j * 256;
            ((float4*)Ws)[idx4] = ((const float4*)W2)[kc * 2048 + idx4];
        }
        __syncthreads();
#pragma unroll
        for (int k4 = 0; k4 < 8; ++k4) {
            float w0 = Ws[(k4 * 4 + 0) * 256 + c];
            float w1 = Ws[(k4 * 4 + 1) * 256 + c];
            float w2 = Ws[(k4 * 4 + 2) * 256 + c];
            float w3 = Ws[(k4 * 4 + 3) * 256 + c];
#pragma unroll
            for (int rr = 0; rr < 32; ++rr) {
                float4 x = *(const float4*)&Xs[rr * 128 + kc * 32 + k4 * 4];
                acc[rr] = fmaf(x.x, w0, acc[rr]);
                acc[rr] = fmaf(x.y, w1, acc[rr]);
                acc[rr] = fmaf(x.z, w2, acc[rr]);
                acc[rr] = fmaf(x.w, w3, acc[rr]);
            }
        }
    }
    float s = 0.f, q = 0.f;
#pragma unroll
    for (int rr = 0; rr < 32; ++rr) {
        int r = row0 + rr;
        if (r < M) yout[(size_t)r * 256 + c] = acc[rr];
        s += acc[rr];
        q += acc[rr] * acc[rr];
    }
    p2sum[(size_t)blockIdx.x * 256 + c] = s;
    p2sq[(size_t)blockIdx.x * 256 + c] = q;
}

// ---------------- in-place BN2+ReLU on the x output region ----------------
__global__ void apply2_kernel(float4* __restrict__ x, const float* __restrict__ scale2,
                              const float* __restrict__ shift2, int n4) {
    int i = blockIdx.x * blockDim.x + threadIdx.x;
    if (i >= n4) return;
    int c4 = i & 63;
    float4 v = x[i];
    float4 sc = ((const float4*)scale2)[c4];
    float4 sh = ((const float4*)shift2)[c4];
    v.x = fmaxf(0.f, fmaf(v.x, sc.x, sh.x));
    v.y = fmaxf(0.f, fmaf(v.y, sc.y, sh.y));
    v.z = fmaxf(0.f, fmaf(v.z, sc.z, sh.z));
    v.w = fmaxf(0.f, fmaf(v.w, sc.w, sh.w));
    x[i] = v;
}

extern "C" void kernel_launch(void* const* d_in, const int* in_sizes, int n_in,
                              void* d_out, int out_size, void* d_ws, size_t ws_size,
                              hipStream_t stream) {
    const float* bxyz  = (const float*)d_in[0];
    const float* feat  = (const float*)d_in[1];
    const int*   sidx  = (const int*)d_in[2];
    const int*   e_point = (const int*)d_in[3];
    const int*   e_new = (const int*)d_in[4];
    const float* W0    = (const float*)d_in[5];
    const float* b0    = (const float*)d_in[6];
    const float* W1    = (const float*)d_in[7];
    const float* g1    = (const float*)d_in[9];
    const float* beta1 = (const float*)d_in[10];
    const float* W2    = (const float*)d_in[11];
    const float* g2    = (const float*)d_in[13];
    const float* beta2 = (const float*)d_in[14];
    int M = in_sizes[2];
    int E = in_sizes[3];

    float* out0 = (float*)d_out;                       // new_bxyz [M,4]
    float* out1 = (float*)d_out + (size_t)M * 4;       // x [M,256] (y2 raw, then in-place BN)

    float* ws = (float*)d_ws;
    size_t o = 0;
    float* agg = ws + o; o += (size_t)M * 64;
    float* y1  = ws + o; o += (size_t)M * 128;
    int nblk1 = (M + 63) / 64;
    int nblk2 = (M + 31) / 32;
    float* p1sum = ws + o; o += (size_t)nblk1 * 128;
    float* p1sq  = ws + o; o += (size_t)nblk1 * 128;
    float* p2sum = ws + o; o += (size_t)nblk2 * 256;
    float* p2sq  = ws + o; o += (size_t)nblk2 * 256;
    float* scale1 = ws + o; o += 128;
    float* shift1 = ws + o; o += 128;
    float* scale2 = ws + o; o += 256;
    float* shift2 = ws + o; o += 256;

    hipMemsetAsync(agg, 0, (size_t)M * 64 * sizeof(float), stream);
    gather_kernel<<<(M + 255) / 256, 256, 0, stream>>>((const float4*)bxyz, sidx, (float4*)out0, M);
    int nwaves = (E + CHUNK - 1) / CHUNK;
    edge_kernel<<<(nwaves + 3) / 4, 256, 0, stream>>>(bxyz, feat, e_point, e_new, out0, W0, b0, agg, E);
    gemm1_kernel<<<nblk1, 256, 0, stream>>>(agg, W1, y1, p1sum, p1sq, M);
    stats_kernel<<<128, 256, 0, stream>>>(p1sum, p1sq, g1, beta1, scale1, shift1, nblk1, 128, 1.f / M);
    gemm2_kernel<<<nblk2, 256, 0, stream>>>(y1, W2, scale1, shift1, out1, p2sum, p2sq, M);
    stats_kernel<<<256, 256, 0, stream>>>(p2sum, p2sq, g2, beta2, scale2, shift2, nblk2, 256, 1.f / M);
    apply2_kernel<<<((M * 64) + 255) / 256, 256, 0, stream>>>((float4*)out1, scale2, shift2, M * 64);
}

// Round 2
// 648.158 us; speedup vs baseline: 2.2738x; 2.2738x over previous
//
#include <hip/hip_runtime.h>

#define EPS 1e-5f
#define ECHUNK 64

// ---------------- new_bxyz gather: out0[i] = point_bxyz[sample_idx[i]] ----------------
__global__ void gather_kernel(const float4* __restrict__ bxyz, const int* __restrict__ sidx,
                              float4* __restrict__ out, int M) {
    int i = blockIdx.x * blockDim.x + threadIdx.x;
    if (i < M) out[i] = bxyz[sidx[i]];
}

// ---------------- per-point projection: G = feat @ W0[3:64,:] + b0  [N,61]@[61,64] ----------------
// block: 64 rows x 64 cols, thread tile 4x4. Xt transposed [k][r] pad 68, Ws [k][c].
__global__ __launch_bounds__(256, 4) void point_kernel(
    const float* __restrict__ feat, const float* __restrict__ W0, const float* __restrict__ b0,
    float* __restrict__ G, int N) {
    __shared__ float Xt[64 * 68];
    __shared__ float Ws[64 * 64];
    int t = threadIdx.x;
    int row0 = blockIdx.x * 64;
    for (int i = t; i < 64 * 61; i += 256) {
        int r = i / 61, k = i - r * 61;
        Xt[k * 68 + r] = feat[(size_t)(row0 + r) * 61 + k];
    }
    for (int i = t; i < 61 * 64; i += 256) {
        int k = i >> 6, c = i & 63;
        Ws[i] = W0[(size_t)(3 + k) * 64 + c];
    }
    if (t < 192) { int k = 61 + t / 64, j = t % 64; Xt[k * 68 + j] = 0.f; Ws[k * 64 + j] = 0.f; }
    __syncthreads();
    int c0 = (t & 15) * 4;
    int r0 = (t >> 4) * 4;
    float acc[4][4] = {};
#pragma unroll 4
    for (int k = 0; k < 64; ++k) {
        float4 x = *(const float4*)&Xt[k * 68 + r0];
        float4 w = *(const float4*)&Ws[k * 64 + c0];
        float xv[4] = {x.x, x.y, x.z, x.w};
        float wv[4] = {w.x, w.y, w.z, w.w};
#pragma unroll
        for (int rr = 0; rr < 4; ++rr)
#pragma unroll
            for (int cc = 0; cc < 4; ++cc)
                acc[rr][cc] = fmaf(xv[rr], wv[cc], acc[rr][cc]);
    }
    float4 bb = *(const float4*)&b0[c0];
#pragma unroll
    for (int rr = 0; rr < 4; ++rr) {
        int r = row0 + r0 + rr;
        if (r < N)
            *(float4*)&G[(size_t)r * 64 + c0] = make_float4(acc[rr][0] + bb.x, acc[rr][1] + bb.y,
                                                            acc[rr][2] + bb.z, acc[rr][3] + bb.w);
    }
}

// ---------------- edge pass: h = G[p] + rel . W0[0:3]; segmented max into agg ----------------
// lane c = channel c. wave processes ECHUNK edges serially; e_new sorted -> run flush via atomicMax.
__global__ __launch_bounds__(256, 4) void edge_kernel(
    const float4* __restrict__ bxyz4, const float4* __restrict__ nbxyz4,
    const int* __restrict__ e_point, const int* __restrict__ e_new,
    const float* __restrict__ G, const float* __restrict__ W0,
    float* __restrict__ agg, int E) {
    int lane = threadIdx.x & 63;
    int gwave = blockIdx.x * 4 + (threadIdx.x >> 6);
    int base = gwave * ECHUNK;
    if (base >= E) return;
    int n = min(ECHUNK, E - base);
    int idx = min(base + lane, E - 1);
    int ep = e_point[idx];
    int en = e_new[idx];
    float wx = W0[lane], wy = W0[64 + lane], wz = W0[128 + lane];
    float runmax = 0.f;      // segment_max(relu(h)) == max(0, max h_pre); empty -> 0
    int curseg = -1;
    float4 Q = make_float4(0.f, 0.f, 0.f, 0.f);
#pragma unroll 4
    for (int e = 0; e < ECHUNK; ++e) {
        if (e >= n) break;
        int p = __builtin_amdgcn_readlane(ep, e);
        int s = __builtin_amdgcn_readlane(en, e);
        if (s != curseg) {
            if (curseg >= 0)
                atomicMax((int*)&agg[(size_t)curseg * 64 + lane], __float_as_int(runmax));
            curseg = s;
            runmax = 0.f;
            Q = nbxyz4[s];
        }
        float4 P = bxyz4[p];
        float g = G[(size_t)p * 64 + lane];
        float h = fmaf(P.y - Q.y, wx, fmaf(P.z - Q.z, wy, fmaf(P.w - Q.w, wz, g)));
        runmax = fmaxf(runmax, h);
    }
    if (curseg >= 0)
        atomicMax((int*)&agg[(size_t)curseg * 64 + lane], __float_as_int(runmax));
}

// ---------------- GEMM1: y1 = agg @ W1 + moment partials. 64x128 tile, thread 4x8 ----------------
__global__ __launch_bounds__(256, 4) void gemm1_kernel(
    const float* __restrict__ agg, const float* __restrict__ W1,
    float* __restrict__ y1, float* __restrict__ p1sum, float* __restrict__ p1sq, int M) {
    __shared__ float Xt[64 * 68];    // [k][r]; aliased as red[] after K loop (4352 floats)
    __shared__ float Ws[64 * 128];   // [k][c]
    float* red = Xt;
    int t = threadIdx.x;
    int row0 = blockIdx.x * 64;
#pragma unroll
    for (int j = 0; j < 4; ++j) {
        int idx4 = t + j * 256;          // 1024 float4 = 64 rows x 16
        int r = idx4 >> 4, k4 = idx4 & 15;
        float4 v = make_float4(0.f, 0.f, 0.f, 0.f);
        if (row0 + r < M) v = ((const float4*)agg)[(size_t)(row0 + r) * 16 + k4];
        Xt[(k4 * 4 + 0) * 68 + r] = v.x;
        Xt[(k4 * 4 + 1) * 68 + r] = v.y;
        Xt[(k4 * 4 + 2) * 68 + r] = v.z;
        Xt[(k4 * 4 + 3) * 68 + r] = v.w;
    }
#pragma unroll
    for (int j = 0; j < 8; ++j) {
        int idx4 = t + j * 256;
        ((float4*)Ws)[idx4] = ((const float4*)W1)[idx4];
    }
    __syncthreads();
    int c0 = (t & 15) * 8;
    int r0 = (t >> 4) * 4;
    float acc[4][8] = {};
#pragma unroll 4
    for (int k = 0; k < 64; ++k) {
        float4 x = *(const float4*)&Xt[k * 68 + r0];
        float4 wa = *(const float4*)&Ws[k * 128 + c0];
        float4 wb = *(const float4*)&Ws[k * 128 + c0 + 4];
        float xv[4] = {x.x, x.y, x.z, x.w};
        float wv[8] = {wa.x, wa.y, wa.z, wa.w, wb.x, wb.y, wb.z, wb.w};
#pragma unroll
        for (int rr = 0; rr < 4; ++rr)
#pragma unroll
            for (int cc = 0; cc < 8; ++cc)
                acc[rr][cc] = fmaf(xv[rr], wv[cc], acc[rr][cc]);
    }
    float s[8] = {}, q[8] = {};
#pragma unroll
    for (int rr = 0; rr < 4; ++rr) {
        int r = row0 + r0 + rr;
        if (r < M) {
            *(float4*)&y1[(size_t)r * 128 + c0] = make_float4(acc[rr][0], acc[rr][1], acc[rr][2], acc[rr][3]);
            *(float4*)&y1[(size_t)r * 128 + c0 + 4] = make_float4(acc[rr][4], acc[rr][5], acc[rr][6], acc[rr][7]);
        }
#pragma unroll
        for (int cc = 0; cc < 8; ++cc) { float a = acc[rr][cc]; s[cc] += a; q[cc] += a * a; }
    }
    __syncthreads();   // Xt reads done; safe to alias as red
    int colg = t & 15, rowg = t >> 4;
#pragma unroll
    for (int cc = 0; cc < 8; ++cc) {
        int c = colg * 8 + cc;
        red[c * 17 + rowg] = s[cc];
        red[2176 + c * 17 + rowg] = q[cc];
    }
    __syncthreads();
    if (t < 128) {
        float ss = 0.f, qq = 0.f;
#pragma unroll
        for (int i = 0; i < 16; ++i) { ss += red[t * 17 + i]; qq += red[2176 + t * 17 + i]; }
        p1sum[(size_t)blockIdx.x * 128 + t] = ss;
        p1sq[(size_t)blockIdx.x * 128 + t] = qq;
    }
}

// ---------------- reduce moment partials -> per-channel BN scale/shift ----------------
__global__ void stats_kernel(const float* __restrict__ psum, const float* __restrict__ psq,
                             const float* __restrict__ g, const float* __restrict__ beta,
                             float* __restrict__ scale, float* __restrict__ shift,
                             int nblk, int ncols, float invM) {
    __shared__ float ss[256], qq[256];
    int c = blockIdx.x;
    int t = threadIdx.x;
    float s = 0.f, q = 0.f;
    for (int b = t; b < nblk; b += 256) {
        s += psum[(size_t)b * ncols + c];
        q += psq[(size_t)b * ncols + c];
    }
    ss[t] = s; qq[t] = q;
    __syncthreads();
    for (int off = 128; off > 0; off >>= 1) {
        if (t < off) { ss[t] += ss[t + off]; qq[t] += qq[t + off]; }
        __syncthreads();
    }
    if (t == 0) {
        float mean = ss[0] * invM;
        float var = qq[0] * invM - mean * mean;
        float sc = g[c] * rsqrtf(var + EPS);
        scale[c] = sc;
        shift[c] = beta[c] - mean * sc;
    }
}

// ---------------- GEMM2: y2 = bnrelu1(y1) @ W2 -> out1 (raw) + moment partials ----------------
// block 64 rows x 256 cols, thread 8x8, K=128 in 4 chunks of 32.
__global__ __launch_bounds__(256, 2) void gemm2_kernel(
    const float* __restrict__ y1, const float* __restrict__ W2,
    const float* __restrict__ scale1, const float* __restrict__ shift1,
    float* __restrict__ yout, float* __restrict__ p2sum, float* __restrict__ p2sq, int M) {
    __shared__ float Xt[128 * 68];   // [k][r]; aliased as red (needs 4608 <= 8704 floats)
    __shared__ float Ws[32 * 256];   // [k][c] chunk
    float* red = Xt;
    int t = threadIdx.x;
    int row0 = blockIdx.x * 64;
#pragma unroll
    for (int j = 0; j < 8; ++j) {
        int idx4 = t + j * 256;          // 2048 float4 = 64 rows x 32
        int r = idx4 >> 5, k4 = idx4 & 31;
        float4 v = make_float4(0.f, 0.f, 0.f, 0.f);
        if (row0 + r < M) {
            float4 y = ((const float4*)y1)[(size_t)(row0 + r) * 32 + k4];
            float4 sc = ((const float4*)scale1)[k4];
            float4 sh = ((const float4*)shift1)[k4];
            v.x = fmaxf(0.f, fmaf(y.x, sc.x, sh.x));
            v.y = fmaxf(0.f, fmaf(y.y, sc.y, sh.y));
            v.z = fmaxf(0.f, fmaf(y.z, sc.z, sh.z));
            v.w = fmaxf(0.f, fmaf(y.w, sc.w, sh.w));
        }
        Xt[(k4 * 4 + 0) * 68 + r] = v.x;
        Xt[(k4 * 4 + 1) * 68 + r] = v.y;
        Xt[(k4 * 4 + 2) * 68 + r] = v.z;
        Xt[(k4 * 4 + 3) * 68 + r] = v.w;
    }
    int c0 = (t & 31) * 8;
    int r0 = (t >> 5) * 8;
    float acc[8][8] = {};
    for (int kc = 0; kc < 4; ++kc) {
        __syncthreads();   // Xt ready (kc==0) / prev Ws consumed
#pragma unroll
        for (int j = 0; j < 8; ++j) {
            int idx4 = t + j * 256;
            ((float4*)Ws)[idx4] = ((const float4*)W2)[kc * 2048 + idx4];
        }
        __syncthreads();
#pragma unroll 2
        for (int k = 0; k < 32; ++k) {
            int kk = kc * 32 + k;
            float4 xa = *(const float4*)&Xt[kk * 68 + r0];
            float4 xb = *(const float4*)&Xt[kk * 68 + r0 + 4];
            float4 wa = *(const float4*)&Ws[k * 256 + c0];
            float4 wb = *(const float4*)&Ws[k * 256 + c0 + 4];
            float xv[8] = {xa.x, xa.y, xa.z, xa.w, xb.x, xb.y, xb.z, xb.w};
            float wv[8] = {wa.x, wa.y, wa.z, wa.w, wb.x, wb.y, wb.z, wb.w};
#pragma unroll
            for (int rr = 0; rr < 8; ++rr)
#pragma unroll
                for (int cc = 0; cc < 8; ++cc)
                    acc[rr][cc] = fmaf(xv[rr], wv[cc], acc[rr][cc]);
        }
    }
    float s[8] = {}, q[8] = {};
#pragma unroll
    for (int rr = 0; rr < 8; ++rr) {
        int r = row0 + r0 + rr;
        if (r < M) {
            *(float4*)&yout[(size_t)r * 256 + c0] = make_float4(acc[rr][0], acc[rr][1], acc[rr][2], acc[rr][3]);
            *(float4*)&yout[(size_t)r * 256 + c0 + 4] = make_float4(acc[rr][4], acc[rr][5], acc[rr][6], acc[rr][7]);
        }
#pragma unroll
        for (int cc = 0; cc < 8; ++cc) { float a = acc[rr][cc]; s[cc] += a; q[cc] += a * a; }
    }
    __syncthreads();   // Xt reads done; alias as red
    int colg = t & 31, rowg = t >> 5;
#pragma unroll
    for (int cc = 0; cc < 8; ++cc) {
        int c = colg * 8 + cc;
        red[c * 9 + rowg] = s[cc];
        red[2304 + c * 9 + rowg] = q[cc];
    }
    __syncthreads();
    float ss = 0.f, qq = 0.f;
#pragma unroll
    for (int i = 0; i < 8; ++i) { ss += red[t * 9 + i]; qq += red[2304 + t * 9 + i]; }
    p2sum[(size_t)blockIdx.x * 256 + t] = ss;
    p2sq[(size_t)blockIdx.x * 256 + t] = qq;
}

// ---------------- in-place BN2+ReLU on the x output region ----------------
__global__ void apply2_kernel(float4* __restrict__ x, const float* __restrict__ scale2,
                              const float* __restrict__ shift2, int n4) {
    int i = blockIdx.x * blockDim.x + threadIdx.x;
    if (i >= n4) return;
    int c4 = i & 63;
    float4 v = x[i];
    float4 sc = ((const float4*)scale2)[c4];
    float4 sh = ((const float4*)shift2)[c4];
    v.x = fmaxf(0.f, fmaf(v.x, sc.x, sh.x));
    v.y = fmaxf(0.f, fmaf(v.y, sc.y, sh.y));
    v.z = fmaxf(0.f, fmaf(v.z, sc.z, sh.z));
    v.w = fmaxf(0.f, fmaf(v.w, sc.w, sh.w));
    x[i] = v;
}

extern "C" void kernel_launch(void* const* d_in, const int* in_sizes, int n_in,
                              void* d_out, int out_size, void* d_ws, size_t ws_size,
                              hipStream_t stream) {
    const float* bxyz  = (const float*)d_in[0];
    const float* feat  = (const float*)d_in[1];
    const int*   sidx  = (const int*)d_in[2];
    const int*   e_point = (const int*)d_in[3];
    const int*   e_new = (const int*)d_in[4];
    const float* W0    = (const float*)d_in[5];
    const float* b0    = (const float*)d_in[6];
    const float* W1    = (const float*)d_in[7];
    const float* g1    = (const float*)d_in[9];
    const float* beta1 = (const float*)d_in[10];
    const float* W2    = (const float*)d_in[11];
    const float* g2    = (const float*)d_in[13];
    const float* beta2 = (const float*)d_in[14];
    int N = in_sizes[0] / 4;     // 400000
    int M = in_sizes[2];         // 100000
    int E = in_sizes[3];         // 3200000

    float* out0 = (float*)d_out;                       // new_bxyz [M,4]
    float* out1 = (float*)d_out + (size_t)M * 4;       // x [M,256]; doubles as G [N,64] early (same size)

    float* G = out1;   // N*64 == M*256 floats; G is dead before gemm2 overwrites out1

    float* ws = (float*)d_ws;
    size_t o = 0;
    float* agg = ws + o; o += (size_t)M * 64;
    float* y1  = ws + o; o += (size_t)M * 128;
    int nblk1 = (M + 63) / 64;
    int nblk2 = (M + 63) / 64;
    float* p1sum = ws + o; o += (size_t)nblk1 * 128;
    float* p1sq  = ws + o; o += (size_t)nblk1 * 128;
    float* p2sum = ws + o; o += (size_t)nblk2 * 256;
    float* p2sq  = ws + o; o += (size_t)nblk2 * 256;
    float* scale1 = ws + o; o += 128;
    float* shift1 = ws + o; o += 128;
    float* scale2 = ws + o; o += 256;
    float* shift2 = ws + o; o += 256;

    hipMemsetAsync(agg, 0, (size_t)M * 64 * sizeof(float), stream);
    gather_kernel<<<(M + 255) / 256, 256, 0, stream>>>((const float4*)bxyz, sidx, (float4*)out0, M);
    point_kernel<<<(N + 63) / 64, 256, 0, stream>>>(feat, W0, b0, G, N);
    int nwaves = (E + ECHUNK - 1) / ECHUNK;
    edge_kernel<<<(nwaves + 3) / 4, 256, 0, stream>>>((const float4*)bxyz, (const float4*)out0,
                                                      e_point, e_new, G, W0, agg, E);
    gemm1_kernel<<<nblk1, 256, 0, stream>>>(agg, W1, y1, p1sum, p1sq, M);
    stats_kernel<<<128, 256, 0, stream>>>(p1sum, p1sq, g1, beta1, scale1, shift1, nblk1, 128, 1.f / M);
    gemm2_kernel<<<nblk2, 256, 0, stream>>>(y1, W2, scale1, shift1, out1, p2sum, p2sq, M);
    stats_kernel<<<256, 256, 0, stream>>>(p2sum, p2sq, g2, beta2, scale2, shift2, nblk2, 256, 1.f / M);
    apply2_kernel<<<((M * 64) + 255) / 256, 256, 0, stream>>>((float4*)out1, scale2, shift2, M * 64);
}

// Round 3
// 548.546 us; speedup vs baseline: 2.6866x; 1.1816x over previous
//
#include <hip/hip_runtime.h>

#define EPS 1e-5f
#define ECHUNK 64
#define PF 8

// ---------------- new_bxyz gather: out0[i] = point_bxyz[sample_idx[i]] ----------------
__global__ void gather_kernel(const float4* __restrict__ bxyz, const int* __restrict__ sidx,
                              float4* __restrict__ out, int M) {
    int i = blockIdx.x * blockDim.x + threadIdx.x;
    if (i < M) out[i] = bxyz[sidx[i]];
}

// ---------------- per-point projection: G = feat @ W0[3:64,:] + b0 -> bf16 [N,64] ----------------
// block: 64 rows x 64 cols, thread tile 4x4. Xt transposed [k][r] pad 68, Ws [k][c].
__global__ __launch_bounds__(256, 4) void point_kernel(
    const float* __restrict__ feat, const float* __restrict__ W0, const float* __restrict__ b0,
    unsigned short* __restrict__ Gb, int N) {
    __shared__ float Xt[64 * 68];
    __shared__ float Ws[64 * 64];
    int t = threadIdx.x;
    int row0 = blockIdx.x * 64;
    for (int i = t; i < 64 * 61; i += 256) {
        int r = i / 61, k = i - r * 61;
        Xt[k * 68 + r] = feat[(size_t)(row0 + r) * 61 + k];
    }
    for (int i = t; i < 61 * 64; i += 256) {
        int k = i >> 6, c = i & 63;
        Ws[i] = W0[(size_t)(3 + k) * 64 + c];
    }
    if (t < 192) { int k = 61 + t / 64, j = t % 64; Xt[k * 68 + j] = 0.f; Ws[k * 64 + j] = 0.f; }
    __syncthreads();
    int c0 = (t & 15) * 4;
    int r0 = (t >> 4) * 4;
    float acc[4][4] = {};
#pragma unroll 4
    for (int k = 0; k < 64; ++k) {
        float4 x = *(const float4*)&Xt[k * 68 + r0];
        float4 w = *(const float4*)&Ws[k * 64 + c0];
        float xv[4] = {x.x, x.y, x.z, x.w};
        float wv[4] = {w.x, w.y, w.z, w.w};
#pragma unroll
        for (int rr = 0; rr < 4; ++rr)
#pragma unroll
            for (int cc = 0; cc < 4; ++cc)
                acc[rr][cc] = fmaf(xv[rr], wv[cc], acc[rr][cc]);
    }
    float4 bb = *(const float4*)&b0[c0];
    float bv[4] = {bb.x, bb.y, bb.z, bb.w};
#pragma unroll
    for (int rr = 0; rr < 4; ++rr) {
        int r = row0 + r0 + rr;
        if (r < N) {
            ushort4 o;
            unsigned short* op = (unsigned short*)&o;
#pragma unroll
            for (int cc = 0; cc < 4; ++cc) {
                float v = acc[rr][cc] + bv[cc];
                // RTNE f32 -> bf16
                unsigned u = __float_as_uint(v);
                unsigned r16 = (u >> 16) + ((u >> 15) & 1u);  // cheap round (ties-away on .5 boundary)
                op[cc] = (unsigned short)r16;
            }
            *(ushort4*)&Gb[(size_t)r * 64 + c0] = o;
        }
    }
}

// ---------------- edge pass: h = G[p] + rel . W0[0:3]; segmented max into agg ----------------
// lane c = channel c. Batch-prefetch PF edges (pure loads), then branchy segment bookkeeping.
__global__ __launch_bounds__(256, 4) void edge_kernel(
    const float4* __restrict__ bxyz4, const float4* __restrict__ nbxyz4,
    const int* __restrict__ e_point, const int* __restrict__ e_new,
    const unsigned short* __restrict__ Gb, const float* __restrict__ W0,
    float* __restrict__ agg, int E) {
    int lane = threadIdx.x & 63;
    int gwave = blockIdx.x * 4 + (threadIdx.x >> 6);
    int base = gwave * ECHUNK;
    if (base >= E) return;
    int n = min(ECHUNK, E - base);
    int idx = min(base + lane, E - 1);
    int ep = e_point[idx];
    int en = e_new[idx];
    float wx = W0[lane], wy = W0[64 + lane], wz = W0[128 + lane];
    float runmax = 0.f;      // segment_max(relu(h)) == max(0, max h_pre); empty -> 0
    int curseg = -1;
    float4 Q = make_float4(0.f, 0.f, 0.f, 0.f);
    for (int g0 = 0; g0 < n; g0 += PF) {
        unsigned short gu[PF];
        float4 Pv[PF];
        // pure-load phase: 2*PF independent loads in flight, no branches/atomics between
#pragma unroll
        for (int j = 0; j < PF; ++j) {
            int p = __builtin_amdgcn_readlane(ep, g0 + j);
            gu[j] = Gb[(size_t)p * 64 + lane];
            Pv[j] = bxyz4[p];
        }
        // bookkeeping phase
#pragma unroll
        for (int j = 0; j < PF; ++j) {
            if (g0 + j >= n) break;
            int s = __builtin_amdgcn_readlane(en, g0 + j);
            if (s != curseg) {
                if (curseg >= 0)
                    atomicMax((int*)&agg[(size_t)curseg * 64 + lane], __float_as_int(runmax));
                curseg = s;
                runmax = 0.f;
                Q = nbxyz4[s];
            }
            float g = __uint_as_float((unsigned)gu[j] << 16);
            float h = fmaf(Pv[j].y - Q.y, wx, fmaf(Pv[j].z - Q.z, wy, fmaf(Pv[j].w - Q.w, wz, g)));
            runmax = fmaxf(runmax, h);
        }
    }
    if (curseg >= 0)
        atomicMax((int*)&agg[(size_t)curseg * 64 + lane], __float_as_int(runmax));
}

// ---------------- GEMM1: y1 = agg @ W1 + moment partials. 64x128 tile, thread 4x8 ----------------
__global__ __launch_bounds__(256, 4) void gemm1_kernel(
    const float* __restrict__ agg, const float* __restrict__ W1,
    float* __restrict__ y1, float* __restrict__ p1sum, float* __restrict__ p1sq, int M) {
    __shared__ float Xt[64 * 68];    // [k][r]; aliased as red[] after K loop (4352 floats)
    __shared__ float Ws[64 * 128];   // [k][c]
    float* red = Xt;
    int t = threadIdx.x;
    int row0 = blockIdx.x * 64;
#pragma unroll
    for (int j = 0; j < 4; ++j) {
        int idx4 = t + j * 256;          // 1024 float4 = 64 rows x 16
        int r = idx4 >> 4, k4 = idx4 & 15;
        float4 v = make_float4(0.f, 0.f, 0.f, 0.f);
        if (row0 + r < M) v = ((const float4*)agg)[(size_t)(row0 + r) * 16 + k4];
        Xt[(k4 * 4 + 0) * 68 + r] = v.x;
        Xt[(k4 * 4 + 1) * 68 + r] = v.y;
        Xt[(k4 * 4 + 2) * 68 + r] = v.z;
        Xt[(k4 * 4 + 3) * 68 + r] = v.w;
    }
#pragma unroll
    for (int j = 0; j < 8; ++j) {
        int idx4 = t + j * 256;
        ((float4*)Ws)[idx4] = ((const float4*)W1)[idx4];
    }
    __syncthreads();
    int c0 = (t & 15) * 8;
    int r0 = (t >> 4) * 4;
    float acc[4][8] = {};
#pragma unroll 4
    for (int k = 0; k < 64; ++k) {
        float4 x = *(const float4*)&Xt[k * 68 + r0];
        float4 wa = *(const float4*)&Ws[k * 128 + c0];
        float4 wb = *(const float4*)&Ws[k * 128 + c0 + 4];
        float xv[4] = {x.x, x.y, x.z, x.w};
        float wv[8] = {wa.x, wa.y, wa.z, wa.w, wb.x, wb.y, wb.z, wb.w};
#pragma unroll
        for (int rr = 0; rr < 4; ++rr)
#pragma unroll
            for (int cc = 0; cc < 8; ++cc)
                acc[rr][cc] = fmaf(xv[rr], wv[cc], acc[rr][cc]);
    }
    float s[8] = {}, q[8] = {};
#pragma unroll
    for (int rr = 0; rr < 4; ++rr) {
        int r = row0 + r0 + rr;
        if (r < M) {
            *(float4*)&y1[(size_t)r * 128 + c0] = make_float4(acc[rr][0], acc[rr][1], acc[rr][2], acc[rr][3]);
            *(float4*)&y1[(size_t)r * 128 + c0 + 4] = make_float4(acc[rr][4], acc[rr][5], acc[rr][6], acc[rr][7]);
        }
#pragma unroll
        for (int cc = 0; cc < 8; ++cc) { float a = acc[rr][cc]; s[cc] += a; q[cc] += a * a; }
    }
    __syncthreads();   // Xt reads done; safe to alias as red
    int colg = t & 15, rowg = t >> 4;
#pragma unroll
    for (int cc = 0; cc < 8; ++cc) {
        int c = colg * 8 + cc;
        red[c * 17 + rowg] = s[cc];
        red[2176 + c * 17 + rowg] = q[cc];
    }
    __syncthreads();
    if (t < 128) {
        float ss = 0.f, qq = 0.f;
#pragma unroll
        for (int i = 0; i < 16; ++i) { ss += red[t * 17 + i]; qq += red[2176 + t * 17 + i]; }
        p1sum[(size_t)blockIdx.x * 128 + t] = ss;
        p1sq[(size_t)blockIdx.x * 128 + t] = qq;
    }
}

// ---------------- reduce moment partials -> per-channel BN scale/shift ----------------
__global__ void stats_kernel(const float* __restrict__ psum, const float* __restrict__ psq,
                             const float* __restrict__ g, const float* __restrict__ beta,
                             float* __restrict__ scale, float* __restrict__ shift,
                             int nblk, int ncols, float invM) {
    __shared__ float ss[256], qq[256];
    int c = blockIdx.x;
    int t = threadIdx.x;
    float s = 0.f, q = 0.f;
    for (int b = t; b < nblk; b += 256) {
        s += psum[(size_t)b * ncols + c];
        q += psq[(size_t)b * ncols + c];
    }
    ss[t] = s; qq[t] = q;
    __syncthreads();
    for (int off = 128; off > 0; off >>= 1) {
        if (t < off) { ss[t] += ss[t + off]; qq[t] += qq[t + off]; }
        __syncthreads();
    }
    if (t == 0) {
        float mean = ss[0] * invM;
        float var = qq[0] * invM - mean * mean;
        float sc = g[c] * rsqrtf(var + EPS);
        scale[c] = sc;
        shift[c] = beta[c] - mean * sc;
    }
}

// ---------------- GEMM2: y2 = bnrelu1(y1) @ W2 -> out1 (raw) + moment partials ----------------
// block 64 rows x 256 cols, thread 8x8, K=128 in 4 chunks of 32.
__global__ __launch_bounds__(256, 2) void gemm2_kernel(
    const float* __restrict__ y1, const float* __restrict__ W2,
    const float* __restrict__ scale1, const float* __restrict__ shift1,
    float* __restrict__ yout, float* __restrict__ p2sum, float* __restrict__ p2sq, int M) {
    __shared__ float Xt[128 * 68];   // [k][r]; aliased as red (needs 4608 <= 8704 floats)
    __shared__ float Ws[32 * 256];   // [k][c] chunk
    float* red = Xt;
    int t = threadIdx.x;
    int row0 = blockIdx.x * 64;
#pragma unroll
    for (int j = 0; j < 8; ++j) {
        int idx4 = t + j * 256;          // 2048 float4 = 64 rows x 32
        int r = idx4 >> 5, k4 = idx4 & 31;
        float4 v = make_float4(0.f, 0.f, 0.f, 0.f);
        if (row0 + r < M) {
            float4 y = ((const float4*)y1)[(size_t)(row0 + r) * 32 + k4];
            float4 sc = ((const float4*)scale1)[k4];
            float4 sh = ((const float4*)shift1)[k4];
            v.x = fmaxf(0.f, fmaf(y.x, sc.x, sh.x));
            v.y = fmaxf(0.f, fmaf(y.y, sc.y, sh.y));
            v.z = fmaxf(0.f, fmaf(y.z, sc.z, sh.z));
            v.w = fmaxf(0.f, fmaf(y.w, sc.w, sh.w));
        }
        Xt[(k4 * 4 + 0) * 68 + r] = v.x;
        Xt[(k4 * 4 + 1) * 68 + r] = v.y;
        Xt[(k4 * 4 + 2) * 68 + r] = v.z;
        Xt[(k4 * 4 + 3) * 68 + r] = v.w;
    }
    int c0 = (t & 31) * 8;
    int r0 = (t >> 5) * 8;
    float acc[8][8] = {};
    for (int kc = 0; kc < 4; ++kc) {
        __syncthreads();   // Xt ready (kc==0) / prev Ws consumed
#pragma unroll
        for (int j = 0; j < 8; ++j) {
            int idx4 = t + j * 256;
            ((float4*)Ws)[idx4] = ((const float4*)W2)[kc * 2048 + idx4];
        }
        __syncthreads();
#pragma unroll 2
        for (int k = 0; k < 32; ++k) {
            int kk = kc * 32 + k;
            float4 xa = *(const float4*)&Xt[kk * 68 + r0];
            float4 xb = *(const float4*)&Xt[kk * 68 + r0 + 4];
            float4 wa = *(const float4*)&Ws[k * 256 + c0];
            float4 wb = *(const float4*)&Ws[k * 256 + c0 + 4];
            float xv[8] = {xa.x, xa.y, xa.z, xa.w, xb.x, xb.y, xb.z, xb.w};
            float wv[8] = {wa.x, wa.y, wa.z, wa.w, wb.x, wb.y, wb.z, wb.w};
#pragma unroll
            for (int rr = 0; rr < 8; ++rr)
#pragma unroll
                for (int cc = 0; cc < 8; ++cc)
                    acc[rr][cc] = fmaf(xv[rr], wv[cc], acc[rr][cc]);
        }
    }
    float s[8] = {}, q[8] = {};
#pragma unroll
    for (int rr = 0; rr < 8; ++rr) {
        int r = row0 + r0 + rr;
        if (r < M) {
            *(float4*)&yout[(size_t)r * 256 + c0] = make_float4(acc[rr][0], acc[rr][1], acc[rr][2], acc[rr][3]);
            *(float4*)&yout[(size_t)r * 256 + c0 + 4] = make_float4(acc[rr][4], acc[rr][5], acc[rr][6], acc[rr][7]);
        }
#pragma unroll
        for (int cc = 0; cc < 8; ++cc) { float a = acc[rr][cc]; s[cc] += a; q[cc] += a * a; }
    }
    __syncthreads();   // Xt reads done; alias as red
    int colg = t & 31, rowg = t >> 5;
#pragma unroll
    for (int cc = 0; cc < 8; ++cc) {
        int c = colg * 8 + cc;
        red[c * 9 + rowg] = s[cc];
        red[2304 + c * 9 + rowg] = q[cc];
    }
    __syncthreads();
    float ss = 0.f, qq = 0.f;
#pragma unroll
    for (int i = 0; i < 8; ++i) { ss += red[t * 9 + i]; qq += red[2304 + t * 9 + i]; }
    p2sum[(size_t)blockIdx.x * 256 + t] = ss;
    p2sq[(size_t)blockIdx.x * 256 + t] = qq;
}

// ---------------- in-place BN2+ReLU on the x output region ----------------
__global__ void apply2_kernel(float4* __restrict__ x, const float* __restrict__ scale2,
                              const float* __restrict__ shift2, int n4) {
    int i = blockIdx.x * blockDim.x + threadIdx.x;
    if (i >= n4) return;
    int c4 = i & 63;
    float4 v = x[i];
    float4 sc = ((const float4*)scale2)[c4];
    float4 sh = ((const float4*)shift2)[c4];
    v.x = fmaxf(0.f, fmaf(v.x, sc.x, sh.x));
    v.y = fmaxf(0.f, fmaf(v.y, sc.y, sh.y));
    v.z = fmaxf(0.f, fmaf(v.z, sc.z, sh.z));
    v.w = fmaxf(0.f, fmaf(v.w, sc.w, sh.w));
    x[i] = v;
}

extern "C" void kernel_launch(void* const* d_in, const int* in_sizes, int n_in,
                              void* d_out, int out_size, void* d_ws, size_t ws_size,
                              hipStream_t stream) {
    const float* bxyz  = (const float*)d_in[0];
    const float* feat  = (const float*)d_in[1];
    const int*   sidx  = (const int*)d_in[2];
    const int*   e_point = (const int*)d_in[3];
    const int*   e_new = (const int*)d_in[4];
    const float* W0    = (const float*)d_in[5];
    const float* b0    = (const float*)d_in[6];
    const float* W1    = (const float*)d_in[7];
    const float* g1    = (const float*)d_in[9];
    const float* beta1 = (const float*)d_in[10];
    const float* W2    = (const float*)d_in[11];
    const float* g2    = (const float*)d_in[13];
    const float* beta2 = (const float*)d_in[14];
    int N = in_sizes[0] / 4;     // 400000
    int M = in_sizes[2];         // 100000
    int E = in_sizes[3];         // 3200000

    float* out0 = (float*)d_out;                       // new_bxyz [M,4]
    float* out1 = (float*)d_out + (size_t)M * 4;       // x [M,256]

    float* ws = (float*)d_ws;
    size_t o = 0;
    float* agg = ws + o; o += (size_t)M * 64;
    float* y1  = ws + o; o += (size_t)M * 128;
    unsigned short* Gb = (unsigned short*)(ws + o); o += (size_t)N * 32;  // bf16 G [N,64]
    int nblk1 = (M + 63) / 64;
    int nblk2 = (M + 63) / 64;
    float* p1sum = ws + o; o += (size_t)nblk1 * 128;
    float* p1sq  = ws + o; o += (size_t)nblk1 * 128;
    float* p2sum = ws + o; o += (size_t)nblk2 * 256;
    float* p2sq  = ws + o; o += (size_t)nblk2 * 256;
    float* scale1 = ws + o; o += 128;
    float* shift1 = ws + o; o += 128;
    float* scale2 = ws + o; o += 256;
    float* shift2 = ws + o; o += 256;

    hipMemsetAsync(agg, 0, (size_t)M * 64 * sizeof(float), stream);
    gather_kernel<<<(M + 255) / 256, 256, 0, stream>>>((const float4*)bxyz, sidx, (float4*)out0, M);
    point_kernel<<<(N + 63) / 64, 256, 0, stream>>>(feat, W0, b0, Gb, N);
    int nwaves = (E + ECHUNK - 1) / ECHUNK;
    edge_kernel<<<(nwaves + 3) / 4, 256, 0, stream>>>((const float4*)bxyz, (const float4*)out0,
                                                      e_point, e_new, Gb, W0, agg, E);
    gemm1_kernel<<<nblk1, 256, 0, stream>>>(agg, W1, y1, p1sum, p1sq, M);
    stats_kernel<<<128, 256, 0, stream>>>(p1sum, p1sq, g1, beta1, scale1, shift1, nblk1, 128, 1.f / M);
    gemm2_kernel<<<nblk2, 256, 0, stream>>>(y1, W2, scale1, shift1, out1, p2sum, p2sq, M);
    stats_kernel<<<256, 256, 0, stream>>>(p2sum, p2sq, g2, beta2, scale2, shift2, nblk2, 256, 1.f / M);
    apply2_kernel<<<((M * 64) + 255) / 256, 256, 0, stream>>>((float4*)out1, scale2, shift2, M * 64);
}

// Round 4
// 463.721 us; speedup vs baseline: 3.1781x; 1.1829x over previous
//
#include <hip/hip_runtime.h>

#define EPS 1e-5f
#define ECHUNK 64
#define PF 8

typedef _Float16 half8 __attribute__((ext_vector_type(8)));
typedef _Float16 half4v __attribute__((ext_vector_type(4)));
typedef float float4v __attribute__((ext_vector_type(4)));

// ---------------- new_bxyz gather: out0[i] = point_bxyz[sample_idx[i]] ----------------
__global__ void gather_kernel(const float4* __restrict__ bxyz, const int* __restrict__ sidx,
                              float4* __restrict__ out, int M) {
    int i = blockIdx.x * blockDim.x + threadIdx.x;
    if (i < M) out[i] = bxyz[sidx[i]];
}

// ---------------- W2 -> f16 transposed [256 n][128 k] ----------------
__global__ void w2t_kernel(const float* __restrict__ W2, _Float16* __restrict__ W2h) {
    int i = blockIdx.x * blockDim.x + threadIdx.x;   // 32768
    int n = i & 255, k = i >> 8;
    W2h[(size_t)n * 128 + k] = (_Float16)W2[(size_t)k * 256 + n];
}

// ---------------- per-point: GD[p][c] = (feat@W0[3:]+b0)[p][c] + P_p . w_c -> fp16 ----------------
__global__ __launch_bounds__(256, 4) void point_kernel(
    const float* __restrict__ feat, const float4* __restrict__ bxyz4,
    const float* __restrict__ W0, const float* __restrict__ b0,
    _Float16* __restrict__ GDh, int N) {
    __shared__ float Xt[64 * 68];
    __shared__ float Ws[64 * 64];
    __shared__ float w0s[192];
    int t = threadIdx.x;
    int row0 = blockIdx.x * 64;
    for (int i = t; i < 64 * 61; i += 256) {
        int r = i / 61, k = i - r * 61;
        int rr = min(row0 + r, N - 1);
        Xt[k * 68 + r] = feat[(size_t)rr * 61 + k];
    }
    for (int i = t; i < 61 * 64; i += 256) {
        int k = i >> 6, c = i & 63;
        Ws[i] = W0[(size_t)(3 + k) * 64 + c];
    }
    if (t < 192) { int k = 61 + t / 64, j = t % 64; Xt[k * 68 + j] = 0.f; Ws[k * 64 + j] = 0.f; w0s[t] = W0[t]; }
    __syncthreads();
    int c0 = (t & 15) * 4;
    int r0 = (t >> 4) * 4;
    float acc[4][4] = {};
#pragma unroll 4
    for (int k = 0; k < 64; ++k) {
        float4 x = *(const float4*)&Xt[k * 68 + r0];
        float4 w = *(const float4*)&Ws[k * 64 + c0];
        float xv[4] = {x.x, x.y, x.z, x.w};
        float wv[4] = {w.x, w.y, w.z, w.w};
#pragma unroll
        for (int rr = 0; rr < 4; ++rr)
#pragma unroll
            for (int cc = 0; cc < 4; ++cc)
                acc[rr][cc] = fmaf(xv[rr], wv[cc], acc[rr][cc]);
    }
    float4 bb = *(const float4*)&b0[c0];
    float bv[4] = {bb.x, bb.y, bb.z, bb.w};
    float wx[4], wy[4], wz[4];
#pragma unroll
    for (int cc = 0; cc < 4; ++cc) {
        wx[cc] = w0s[c0 + cc];
        wy[cc] = w0s[64 + c0 + cc];
        wz[cc] = w0s[128 + c0 + cc];
    }
#pragma unroll
    for (int rr = 0; rr < 4; ++rr) {
        int r = row0 + r0 + rr;
        if (r < N) {
            float4 P = bxyz4[r];
            half4v o;
#pragma unroll
            for (int cc = 0; cc < 4; ++cc) {
                float d = fmaf(P.y, wx[cc], fmaf(P.z, wy[cc], P.w * wz[cc]));
                o[cc] = (_Float16)(acc[rr][cc] + bv[cc] + d);
            }
            *(half4v*)&GDh[(size_t)r * 64 + c0] = o;
        }
    }
}

// ---------------- edge pass: h = GD[p][lane] - Q_s.w_lane; segmented max into agg ----------------
__global__ __launch_bounds__(256, 4) void edge_kernel(
    const float4* __restrict__ nbxyz4,
    const int* __restrict__ e_point, const int* __restrict__ e_new,
    const _Float16* __restrict__ GDh, const float* __restrict__ W0,
    float* __restrict__ agg, int E) {
    int lane = threadIdx.x & 63;
    int gwave = blockIdx.x * 4 + (threadIdx.x >> 6);
    int base = gwave * ECHUNK;
    if (base >= E) return;
    int n = min(ECHUNK, E - base);
    int idx = min(base + lane, E - 1);
    int ep = e_point[idx];
    int en = e_new[idx];
    float wx = W0[lane], wy = W0[64 + lane], wz = W0[128 + lane];
    float runmax = 0.f;      // segment_max(relu(h)) == max(0, max h_pre); empty -> 0
    int curseg = -1;
    float S = 0.f;
    for (int g0 = 0; g0 < n; g0 += PF) {
        _Float16 gu[PF];
        // pure-load phase: PF independent gathers in flight
#pragma unroll
        for (int j = 0; j < PF; ++j) {
            int p = __builtin_amdgcn_readlane(ep, g0 + j);
            gu[j] = GDh[(size_t)p * 64 + lane];
        }
        // bookkeeping phase
#pragma unroll
        for (int j = 0; j < PF; ++j) {
            if (g0 + j >= n) break;
            int s = __builtin_amdgcn_readlane(en, g0 + j);
            if (s != curseg) {
                if (curseg >= 0)
                    atomicMax((int*)&agg[(size_t)curseg * 64 + lane], __float_as_int(runmax));
                curseg = s;
                runmax = 0.f;
                float4 Q = nbxyz4[s];
                S = fmaf(Q.y, wx, fmaf(Q.z, wy, Q.w * wz));
            }
            float h = (float)gu[j] - S;
            runmax = fmaxf(runmax, h);
        }
    }
    if (curseg >= 0)
        atomicMax((int*)&agg[(size_t)curseg * 64 + lane], __float_as_int(runmax));
}

// ---------------- GEMM1: y1 = agg @ W1 + moment partials. 64x128 tile, thread 4x8 ----------------
__global__ __launch_bounds__(256, 4) void gemm1_kernel(
    const float* __restrict__ agg, const float* __restrict__ W1,
    float* __restrict__ y1, float* __restrict__ p1sum, float* __restrict__ p1sq, int M) {
    __shared__ float Xt[64 * 68];    // [k][r]; aliased as red[] after K loop
    __shared__ float Ws[64 * 128];   // [k][c]
    float* red = Xt;
    int t = threadIdx.x;
    int row0 = blockIdx.x * 64;
#pragma unroll
    for (int j = 0; j < 4; ++j) {
        int idx4 = t + j * 256;
        int r = idx4 >> 4, k4 = idx4 & 15;
        float4 v = make_float4(0.f, 0.f, 0.f, 0.f);
        if (row0 + r < M) v = ((const float4*)agg)[(size_t)(row0 + r) * 16 + k4];
        Xt[(k4 * 4 + 0) * 68 + r] = v.x;
        Xt[(k4 * 4 + 1) * 68 + r] = v.y;
        Xt[(k4 * 4 + 2) * 68 + r] = v.z;
        Xt[(k4 * 4 + 3) * 68 + r] = v.w;
    }
#pragma unroll
    for (int j = 0; j < 8; ++j) {
        int idx4 = t + j * 256;
        ((float4*)Ws)[idx4] = ((const float4*)W1)[idx4];
    }
    __syncthreads();
    int c0 = (t & 15) * 8;
    int r0 = (t >> 4) * 4;
    float acc[4][8] = {};
#pragma unroll 4
    for (int k = 0; k < 64; ++k) {
        float4 x = *(const float4*)&Xt[k * 68 + r0];
        float4 wa = *(const float4*)&Ws[k * 128 + c0];
        float4 wb = *(const float4*)&Ws[k * 128 + c0 + 4];
        float xv[4] = {x.x, x.y, x.z, x.w};
        float wv[8] = {wa.x, wa.y, wa.z, wa.w, wb.x, wb.y, wb.z, wb.w};
#pragma unroll
        for (int rr = 0; rr < 4; ++rr)
#pragma unroll
            for (int cc = 0; cc < 8; ++cc)
                acc[rr][cc] = fmaf(xv[rr], wv[cc], acc[rr][cc]);
    }
    float s[8] = {}, q[8] = {};
#pragma unroll
    for (int rr = 0; rr < 4; ++rr) {
        int r = row0 + r0 + rr;
        if (r < M) {
            *(float4*)&y1[(size_t)r * 128 + c0] = make_float4(acc[rr][0], acc[rr][1], acc[rr][2], acc[rr][3]);
            *(float4*)&y1[(size_t)r * 128 + c0 + 4] = make_float4(acc[rr][4], acc[rr][5], acc[rr][6], acc[rr][7]);
        }
#pragma unroll
        for (int cc = 0; cc < 8; ++cc) { float a = acc[rr][cc]; s[cc] += a; q[cc] += a * a; }
    }
    __syncthreads();
    int colg = t & 15, rowg = t >> 4;
#pragma unroll
    for (int cc = 0; cc < 8; ++cc) {
        int c = colg * 8 + cc;
        red[c * 17 + rowg] = s[cc];
        red[2176 + c * 17 + rowg] = q[cc];
    }
    __syncthreads();
    if (t < 128) {
        float ss = 0.f, qq = 0.f;
#pragma unroll
        for (int i = 0; i < 16; ++i) { ss += red[t * 17 + i]; qq += red[2176 + t * 17 + i]; }
        p1sum[(size_t)blockIdx.x * 128 + t] = ss;
        p1sq[(size_t)blockIdx.x * 128 + t] = qq;
    }
}

// ---------------- reduce moment partials -> per-channel BN scale/shift ----------------
__global__ void stats_kernel(const float* __restrict__ psum, const float* __restrict__ psq,
                             const float* __restrict__ g, const float* __restrict__ beta,
                             float* __restrict__ scale, float* __restrict__ shift,
                             int nblk, int ncols, float invM) {
    __shared__ float ss[256], qq[256];
    int c = blockIdx.x;
    int t = threadIdx.x;
    float s = 0.f, q = 0.f;
    for (int b = t; b < nblk; b += 256) {
        s += psum[(size_t)b * ncols + c];
        q += psq[(size_t)b * ncols + c];
    }
    ss[t] = s; qq[t] = q;
    __syncthreads();
    for (int off = 128; off > 0; off >>= 1) {
        if (t < off) { ss[t] += ss[t + off]; qq[t] += qq[t + off]; }
        __syncthreads();
    }
    if (t == 0) {
        float mean = ss[0] * invM;
        float var = qq[0] * invM - mean * mean;
        float sc = g[c] * rsqrtf(var + EPS);
        scale[c] = sc;
        shift[c] = beta[c] - mean * sc;
    }
}

// ---------------- GEMM2 (f16 MFMA): y2 = bnrelu1(y1) @ W2 -> out1 + moment partials ----------------
// block = 128M x 128N, 4 waves each 64M x 64N, K=128 fully staged in LDS.
__global__ __launch_bounds__(256, 2) void gemm2_kernel(
    const float* __restrict__ y1, const _Float16* __restrict__ W2h,
    const float* __restrict__ scale1, const float* __restrict__ shift1,
    float* __restrict__ yout, float* __restrict__ p2sum, float* __restrict__ p2sq,
    int M, int nbn) {
    __shared__ _Float16 As[128 * 136];   // [m][k] pad 8 halves
    __shared__ _Float16 Bs[128 * 136];   // [n][k] pad 8 halves
    int t = threadIdx.x;
    int bm = blockIdx.x / nbn;
    int bn = blockIdx.x % nbn;
    int row0 = bm * 128;
    // stage A: bnrelu1(y1) -> f16
#pragma unroll
    for (int j = 0; j < 16; ++j) {
        int idx4 = t + j * 256;            // 4096 float4 = 128 rows x 32
        int r = idx4 >> 5, k4 = idx4 & 31;
        float4 v = make_float4(0.f, 0.f, 0.f, 0.f);
        if (row0 + r < M) {
            float4 y = ((const float4*)y1)[(size_t)(row0 + r) * 32 + k4];
            float4 sc = ((const float4*)scale1)[k4];
            float4 sh = ((const float4*)shift1)[k4];
            v.x = fmaxf(0.f, fmaf(y.x, sc.x, sh.x));
            v.y = fmaxf(0.f, fmaf(y.y, sc.y, sh.y));
            v.z = fmaxf(0.f, fmaf(y.z, sc.z, sh.z));
            v.w = fmaxf(0.f, fmaf(y.w, sc.w, sh.w));
        }
        half4v h;
        h[0] = (_Float16)v.x; h[1] = (_Float16)v.y; h[2] = (_Float16)v.z; h[3] = (_Float16)v.w;
        *(half4v*)&As[r * 136 + k4 * 4] = h;
    }
    // stage B: W2h rows n0..n0+127 (16B per thread-iter)
    int n0 = bn * 128;
#pragma unroll
    for (int j = 0; j < 8; ++j) {
        int idx8 = t + j * 256;            // 2048 x (8 halves) = 128 n x 16
        int nn = idx8 >> 4, k8 = idx8 & 15;
        *(half8*)&Bs[nn * 136 + k8 * 8] = *(const half8*)&W2h[(size_t)(n0 + nn) * 128 + k8 * 8];
    }
    __syncthreads();
    int w = t >> 6, lane = t & 63;
    int quad = lane >> 4, l16 = lane & 15;
    int mwave = (w >> 1) * 64, nwave = (w & 1) * 64;
    float4v acc[4][4] = {};   // [mt][nt]
#pragma unroll
    for (int kc = 0; kc < 4; ++kc) {
        int koff = kc * 32 + quad * 8;
        half8 af[4], bf[4];
#pragma unroll
        for (int mt = 0; mt < 4; ++mt)
            af[mt] = *(const half8*)&As[(mwave + mt * 16 + l16) * 136 + koff];
#pragma unroll
        for (int nt = 0; nt < 4; ++nt)
            bf[nt] = *(const half8*)&Bs[(nwave + nt * 16 + l16) * 136 + koff];
#pragma unroll
        for (int mt = 0; mt < 4; ++mt)
#pragma unroll
            for (int nt = 0; nt < 4; ++nt)
                acc[mt][nt] = __builtin_amdgcn_mfma_f32_16x16x32_f16(af[mt], bf[nt], acc[mt][nt], 0, 0, 0);
    }
    // write y2 fp32 + accumulate per-lane column partials
    float s[4] = {}, q[4] = {};
    int colbase = n0 + nwave + l16;
#pragma unroll
    for (int mt = 0; mt < 4; ++mt) {
#pragma unroll
        for (int i = 0; i < 4; ++i) {
            int row = row0 + mwave + mt * 16 + quad * 4 + i;
            if (row < M) {
#pragma unroll
                for (int nt = 0; nt < 4; ++nt)
                    yout[(size_t)row * 256 + colbase + nt * 16] = acc[mt][nt][i];
            }
#pragma unroll
            for (int nt = 0; nt < 4; ++nt) {
                float a = acc[mt][nt][i];   // padded rows are exactly 0 -> harmless
                s[nt] += a; q[nt] += a * a;
            }
        }
    }
    __syncthreads();   // all LDS frag reads done; alias As as reduction buffer
    float* red = (float*)As;   // [128 cols][8 slots] sum, then sq at +1024
    int slot = (w >> 1) * 4 + quad;
#pragma unroll
    for (int nt = 0; nt < 4; ++nt) {
        int c = (w & 1) * 64 + nt * 16 + l16;
        red[c * 8 + slot] = s[nt];
        red[1024 + c * 8 + slot] = q[nt];
    }
    __syncthreads();
    if (t < 128) {
        float ss = 0.f, qq = 0.f;
#pragma unroll
        for (int i = 0; i < 8; ++i) { ss += red[t * 8 + i]; qq += red[1024 + t * 8 + i]; }
        p2sum[(size_t)bm * 256 + n0 + t] = ss;
        p2sq[(size_t)bm * 256 + n0 + t] = qq;
    }
}

// ---------------- in-place BN2+ReLU on the x output region ----------------
__global__ void apply2_kernel(float4* __restrict__ x, const float* __restrict__ scale2,
                              const float* __restrict__ shift2, int n4) {
    int i = blockIdx.x * blockDim.x + threadIdx.x;
    if (i >= n4) return;
    int c4 = i & 63;
    float4 v = x[i];
    float4 sc = ((const float4*)scale2)[c4];
    float4 sh = ((const float4*)shift2)[c4];
    v.x = fmaxf(0.f, fmaf(v.x, sc.x, sh.x));
    v.y = fmaxf(0.f, fmaf(v.y, sc.y, sh.y));
    v.z = fmaxf(0.f, fmaf(v.z, sc.z, sh.z));
    v.w = fmaxf(0.f, fmaf(v.w, sc.w, sh.w));
    x[i] = v;
}

extern "C" void kernel_launch(void* const* d_in, const int* in_sizes, int n_in,
                              void* d_out, int out_size, void* d_ws, size_t ws_size,
                              hipStream_t stream) {
    const float* bxyz  = (const float*)d_in[0];
    const float* feat  = (const float*)d_in[1];
    const int*   sidx  = (const int*)d_in[2];
    const int*   e_point = (const int*)d_in[3];
    const int*   e_new = (const int*)d_in[4];
    const float* W0    = (const float*)d_in[5];
    const float* b0    = (const float*)d_in[6];
    const float* W1    = (const float*)d_in[7];
    const float* g1    = (const float*)d_in[9];
    const float* beta1 = (const float*)d_in[10];
    const float* W2    = (const float*)d_in[11];
    const float* g2    = (const float*)d_in[13];
    const float* beta2 = (const float*)d_in[14];
    int N = in_sizes[0] / 4;     // 400000
    int M = in_sizes[2];         // 100000
    int E = in_sizes[3];         // 3200000

    float* out0 = (float*)d_out;                       // new_bxyz [M,4]
    float* out1 = (float*)d_out + (size_t)M * 4;       // x [M,256]

    float* ws = (float*)d_ws;
    size_t o = 0;
    float* agg = ws + o; o += (size_t)M * 64;
    float* y1  = ws + o; o += (size_t)M * 128;
    _Float16* GDh = (_Float16*)(ws + o); o += (size_t)N * 32;   // fp16 GD [N,64]
    _Float16* W2h = (_Float16*)(ws + o); o += 128 * 256 / 2;    // fp16 W2^T [256,128]
    int nblk1 = (M + 63) / 64;
    int nblk2m = (M + 127) / 128;
    int nbn = 2;
    float* p1sum = ws + o; o += (size_t)nblk1 * 128;
    float* p1sq  = ws + o; o += (size_t)nblk1 * 128;
    float* p2sum = ws + o; o += (size_t)nblk2m * 256;
    float* p2sq  = ws + o; o += (size_t)nblk2m * 256;
    float* scale1 = ws + o; o += 128;
    float* shift1 = ws + o; o += 128;
    float* scale2 = ws + o; o += 256;
    float* shift2 = ws + o; o += 256;

    hipMemsetAsync(agg, 0, (size_t)M * 64 * sizeof(float), stream);
    gather_kernel<<<(M + 255) / 256, 256, 0, stream>>>((const float4*)bxyz, sidx, (float4*)out0, M);
    w2t_kernel<<<128, 256, 0, stream>>>(W2, W2h);
    point_kernel<<<(N + 63) / 64, 256, 0, stream>>>(feat, (const float4*)bxyz, W0, b0, GDh, N);
    int nwaves = (E + ECHUNK - 1) / ECHUNK;
    edge_kernel<<<(nwaves + 3) / 4, 256, 0, stream>>>((const float4*)out0, e_point, e_new,
                                                      GDh, W0, agg, E);
    gemm1_kernel<<<nblk1, 256, 0, stream>>>(agg, W1, y1, p1sum, p1sq, M);
    stats_kernel<<<128, 256, 0, stream>>>(p1sum, p1sq, g1, beta1, scale1, shift1, nblk1, 128, 1.f / M);
    gemm2_kernel<<<nblk2m * nbn, 256, 0, stream>>>(y1, W2h, scale1, shift1, out1, p2sum, p2sq, M, nbn);
    stats_kernel<<<256, 256, 0, stream>>>(p2sum, p2sq, g2, beta2, scale2, shift2, nblk2m, 256, 1.f / M);
    apply2_kernel<<<((M * 64) + 255) / 256, 256, 0, stream>>>((float4*)out1, scale2, shift2, M * 64);
}

// Round 5
// 404.798 us; speedup vs baseline: 3.6407x; 1.1456x over previous
//
#include <hip/hip_runtime.h>

#define EPS 1e-5f
#define ECHUNK 64
#define PF 8

typedef _Float16 half8 __attribute__((ext_vector_type(8)));
typedef _Float16 half4v __attribute__((ext_vector_type(4)));
typedef float float4v __attribute__((ext_vector_type(4)));

// ---------------- new_bxyz gather: out0[i] = point_bxyz[sample_idx[i]] ----------------
__global__ void gather_kernel(const float4* __restrict__ bxyz, const int* __restrict__ sidx,
                              float4* __restrict__ out, int M) {
    int i = blockIdx.x * blockDim.x + threadIdx.x;
    if (i < M) out[i] = bxyz[sidx[i]];
}

// ---------------- weight prep: W0/W1/W2 -> f16, transposed to [n][k] ----------------
__global__ void prep_kernel(const float* __restrict__ W0, const float* __restrict__ W1,
                            const float* __restrict__ W2, _Float16* __restrict__ W0t,
                            _Float16* __restrict__ W1t, _Float16* __restrict__ W2t) {
    int i = blockIdx.x * blockDim.x + threadIdx.x;
    if (i < 4096) {                    // W0 [64 k][64 n] -> W0t [n][k]
        int k = i >> 6, n = i & 63;
        W0t[(size_t)n * 64 + k] = (_Float16)W0[i];
    } else if (i < 12288) {            // W1 [64 k][128 n] -> W1t [n][k]
        int j = i - 4096; int k = j >> 7, n = j & 127;
        W1t[(size_t)n * 64 + k] = (_Float16)W1[j];
    } else if (i < 45056) {            // W2 [128 k][256 n] -> W2t [n][k]
        int j = i - 12288; int k = j >> 8, n = j & 255;
        W2t[(size_t)n * 128 + k] = (_Float16)W2[j];
    }
}

// ---------------- point (f16 MFMA): GD = [P.yzw ; feat] @ W0 + b0 -> fp16 [N,64] ----------------
// 128 rows/block, K=64 (3 pos + 61 feat), 4 waves x (2 mt x 4 nt) 16x16x32 MFMAs.
__global__ __launch_bounds__(256, 4) void point_kernel(
    const float* __restrict__ feat, const float4* __restrict__ bxyz4,
    const _Float16* __restrict__ W0t, const float* __restrict__ b0,
    _Float16* __restrict__ GDh, int N) {
    __shared__ _Float16 As[128 * 72];   // [r][k] pad 72 (2-way bank alias = free)
    int t = threadIdx.x;
    int row0 = blockIdx.x * 128;
    if (t < 128) {
        int r = min(row0 + t, N - 1);
        float4 P = bxyz4[r];
        As[t * 72 + 0] = (_Float16)P.y;
        As[t * 72 + 1] = (_Float16)P.z;
        As[t * 72 + 2] = (_Float16)P.w;
    }
    // feat tile is flat-contiguous and float4-aligned: row0*61 % 4 == 0 (row0 mult of 128)
    const float* fbase = feat + (size_t)row0 * 61;
    int avail = (int)min((size_t)7808, (size_t)(N - row0) * 61);
#pragma unroll
    for (int j = 0; j < 8; ++j) {
        int base = (t + j * 256) * 4;
        if (base < avail) {
            float4 v = *(const float4*)&fbase[base];
            float fv[4] = {v.x, v.y, v.z, v.w};
#pragma unroll
            for (int u = 0; u < 4; ++u) {
                int flat = base + u;
                int r = flat / 61;
                int k = flat - r * 61;
                As[r * 72 + 3 + k] = (_Float16)fv[u];
            }
        }
    }
    __syncthreads();
    int w = t >> 6, lane = t & 63, quad = lane >> 4, l16 = lane & 15;
    int mwave = w * 32;
    float4v acc[2][4] = {};
#pragma unroll
    for (int kc = 0; kc < 2; ++kc) {
        int koff = kc * 32 + quad * 8;
        half8 af[2], bf[4];
#pragma unroll
        for (int mt = 0; mt < 2; ++mt)
            af[mt] = *(const half8*)&As[(mwave + mt * 16 + l16) * 72 + koff];
#pragma unroll
        for (int nt = 0; nt < 4; ++nt)
            bf[nt] = *(const half8*)&W0t[(size_t)(nt * 16 + l16) * 64 + koff];
#pragma unroll
        for (int mt = 0; mt < 2; ++mt)
#pragma unroll
            for (int nt = 0; nt < 4; ++nt)
                acc[mt][nt] = __builtin_amdgcn_mfma_f32_16x16x32_f16(af[mt], bf[nt], acc[mt][nt], 0, 0, 0);
    }
    float b0v[4];
#pragma unroll
    for (int nt = 0; nt < 4; ++nt) b0v[nt] = b0[nt * 16 + l16];
    __syncthreads();   // all af reads done; reuse As as [r][c] output staging
#pragma unroll
    for (int mt = 0; mt < 2; ++mt)
#pragma unroll
        for (int i = 0; i < 4; ++i) {
            int rloc = mwave + mt * 16 + quad * 4 + i;
#pragma unroll
            for (int nt = 0; nt < 4; ++nt)
                As[rloc * 72 + nt * 16 + l16] = (_Float16)(acc[mt][nt][i] + b0v[nt]);
        }
    __syncthreads();
#pragma unroll
    for (int j = 0; j < 4; ++j) {
        int i8 = t + j * 256;            // 1024 half8 = 128 r x 8
        int r = i8 >> 3, c8 = i8 & 7;
        if (row0 + r < N)
            *(half8*)&GDh[(size_t)(row0 + r) * 64 + c8 * 8] = *(const half8*)&As[r * 72 + c8 * 8];
    }
}

// ---------------- edge pass: h = GD[p][lane] - Q_s.w_lane; segmented max into agg ----------------
__global__ __launch_bounds__(256, 4) void edge_kernel(
    const float4* __restrict__ nbxyz4,
    const int* __restrict__ e_point, const int* __restrict__ e_new,
    const _Float16* __restrict__ GDh, const float* __restrict__ W0,
    float* __restrict__ agg, int E) {
    int lane = threadIdx.x & 63;
    int gwave = blockIdx.x * 4 + (threadIdx.x >> 6);
    int base = gwave * ECHUNK;
    if (base >= E) return;
    int n = min(ECHUNK, E - base);
    int idx = min(base + lane, E - 1);
    int ep = e_point[idx];
    int en = e_new[idx];
    float wx = W0[lane], wy = W0[64 + lane], wz = W0[128 + lane];
    float runmax = 0.f;      // segment_max(relu(h)) == max(0, max h_pre); empty -> 0
    int curseg = -1;
    float S = 0.f;
    for (int g0 = 0; g0 < n; g0 += PF) {
        _Float16 gu[PF];
#pragma unroll
        for (int j = 0; j < PF; ++j) {
            int p = __builtin_amdgcn_readlane(ep, g0 + j);
            gu[j] = GDh[(size_t)p * 64 + lane];
        }
#pragma unroll
        for (int j = 0; j < PF; ++j) {
            if (g0 + j >= n) break;
            int s = __builtin_amdgcn_readlane(en, g0 + j);
            if (s != curseg) {
                if (curseg >= 0)
                    atomicMax((int*)&agg[(size_t)curseg * 64 + lane], __float_as_int(runmax));
                curseg = s;
                runmax = 0.f;
                float4 Q = nbxyz4[s];
                S = fmaf(Q.y, wx, fmaf(Q.z, wy, Q.w * wz));
            }
            float h = (float)gu[j] - S;
            runmax = fmaxf(runmax, h);
        }
    }
    if (curseg >= 0)
        atomicMax((int*)&agg[(size_t)curseg * 64 + lane], __float_as_int(runmax));
}

// ---------------- GEMM1 (f16 MFMA): y1h = agg @ W1 -> f16 [M,128] + moment partials ----------------
// 128 rows/block, K=64, 4 waves x (2 mt x 8 nt).
__global__ __launch_bounds__(256, 2) void gemm1_kernel(
    const float* __restrict__ agg, const _Float16* __restrict__ W1t,
    _Float16* __restrict__ y1h, float* __restrict__ p1sum, float* __restrict__ p1sq, int M) {
    __shared__ _Float16 As[128 * 72];     // [r][k], then reused as [r][c-half] output staging
    __shared__ float red[4096];           // 128 cols x 16 slots, sum + sq
    int t = threadIdx.x;
    int row0 = blockIdx.x * 128;
#pragma unroll
    for (int j = 0; j < 8; ++j) {
        int i4 = t + j * 256;              // 2048 float4 = 128 r x 16
        int r = i4 >> 4, k4 = i4 & 15;
        float4 v = make_float4(0.f, 0.f, 0.f, 0.f);
        if (row0 + r < M) v = ((const float4*)agg)[(size_t)(row0 + r) * 16 + k4];
        half4v h;
        h[0] = (_Float16)v.x; h[1] = (_Float16)v.y; h[2] = (_Float16)v.z; h[3] = (_Float16)v.w;
        *(half4v*)&As[r * 72 + k4 * 4] = h;
    }
    __syncthreads();
    int w = t >> 6, lane = t & 63, quad = lane >> 4, l16 = lane & 15;
    int mwave = w * 32;
    float4v acc[2][8] = {};
#pragma unroll
    for (int kc = 0; kc < 2; ++kc) {
        int koff = kc * 32 + quad * 8;
        half8 af[2], bf[8];
#pragma unroll
        for (int mt = 0; mt < 2; ++mt)
            af[mt] = *(const half8*)&As[(mwave + mt * 16 + l16) * 72 + koff];
#pragma unroll
        for (int nt = 0; nt < 8; ++nt)
            bf[nt] = *(const half8*)&W1t[(size_t)(nt * 16 + l16) * 64 + koff];
#pragma unroll
        for (int mt = 0; mt < 2; ++mt)
#pragma unroll
            for (int nt = 0; nt < 8; ++nt)
                acc[mt][nt] = __builtin_amdgcn_mfma_f32_16x16x32_f16(af[mt], bf[nt], acc[mt][nt], 0, 0, 0);
    }
    // per-col moment partials (padded rows contribute exact 0)
    float s[8] = {}, q[8] = {};
#pragma unroll
    for (int mt = 0; mt < 2; ++mt)
#pragma unroll
        for (int i = 0; i < 4; ++i)
#pragma unroll
            for (int nt = 0; nt < 8; ++nt) {
                float a = acc[mt][nt][i];
                s[nt] += a; q[nt] += a * a;
            }
    int slot = w * 4 + quad;
#pragma unroll
    for (int nt = 0; nt < 8; ++nt) {
        int c = nt * 16 + l16;
        red[c * 16 + slot] = s[nt];
        red[2048 + c * 16 + slot] = q[nt];
    }
    __syncthreads();   // red complete; As frag reads complete
    if (t < 128) {
        float ss = 0.f, qq = 0.f;
#pragma unroll
        for (int i = 0; i < 16; ++i) { ss += red[t * 16 + i]; qq += red[2048 + t * 16 + i]; }
        p1sum[(size_t)blockIdx.x * 128 + t] = ss;
        p1sq[(size_t)blockIdx.x * 128 + t] = qq;
    }
    // y1 writeout via LDS transpose, two 64-col passes
#pragma unroll
    for (int half = 0; half < 2; ++half) {
#pragma unroll
        for (int mt = 0; mt < 2; ++mt)
#pragma unroll
            for (int i = 0; i < 4; ++i) {
                int rloc = mwave + mt * 16 + quad * 4 + i;
#pragma unroll
                for (int nt = 0; nt < 4; ++nt)
                    As[rloc * 72 + nt * 16 + l16] = (_Float16)acc[mt][half * 4 + nt][i];
            }
        __syncthreads();
#pragma unroll
        for (int j = 0; j < 4; ++j) {
            int i8 = t + j * 256;          // 1024 half8 = 128 r x 8
            int r = i8 >> 3, c8 = i8 & 7;
            if (row0 + r < M)
                *(half8*)&y1h[(size_t)(row0 + r) * 128 + half * 64 + c8 * 8] =
                    *(const half8*)&As[r * 72 + c8 * 8];
        }
        __syncthreads();
    }
}

// ---------------- reduce moment partials -> per-channel BN scale/shift ----------------
__global__ void stats_kernel(const float* __restrict__ psum, const float* __restrict__ psq,
                             const float* __restrict__ g, const float* __restrict__ beta,
                             float* __restrict__ scale, float* __restrict__ shift,
                             int nblk, int ncols, float invM) {
    __shared__ float ss[256], qq[256];
    int c = blockIdx.x;
    int t = threadIdx.x;
    float s = 0.f, q = 0.f;
    for (int b = t; b < nblk; b += 256) {
        s += psum[(size_t)b * ncols + c];
        q += psq[(size_t)b * ncols + c];
    }
    ss[t] = s; qq[t] = q;
    __syncthreads();
    for (int off = 128; off > 0; off >>= 1) {
        if (t < off) { ss[t] += ss[t + off]; qq[t] += qq[t + off]; }
        __syncthreads();
    }
    if (t == 0) {
        float mean = ss[0] * invM;
        float var = qq[0] * invM - mean * mean;
        float sc = g[c] * rsqrtf(var + EPS);
        scale[c] = sc;
        shift[c] = beta[c] - mean * sc;
    }
}

// ---------------- GEMM2 (f16 MFMA): y2 = bnrelu1(y1h) @ W2 -> out1 + moment partials ----------------
// block = 128M x 128N, 4 waves each 64M x 64N, K=128 fully staged in LDS.
__global__ __launch_bounds__(256, 2) void gemm2_kernel(
    const _Float16* __restrict__ y1h, const _Float16* __restrict__ W2t,
    const float* __restrict__ scale1, const float* __restrict__ shift1,
    float* __restrict__ yout, float* __restrict__ p2sum, float* __restrict__ p2sq,
    int M, int nbn) {
    __shared__ _Float16 As[128 * 136];   // [m][k] pad 8 halves
    __shared__ _Float16 Bs[128 * 136];   // [n][k] pad 8 halves
    int t = threadIdx.x;
    int bm = blockIdx.x / nbn;
    int bn = blockIdx.x % nbn;
    int row0 = bm * 128;
    // stage A: bnrelu1(y1h) -> f16
#pragma unroll
    for (int j = 0; j < 8; ++j) {
        int i8 = t + j * 256;              // 2048 half8 = 128 r x 16
        int r = i8 >> 4, k8 = i8 & 15;
        half8 hv = {};
        if (row0 + r < M) {
            half8 y = *(const half8*)&y1h[(size_t)(row0 + r) * 128 + k8 * 8];
            float4 sca = ((const float4*)scale1)[k8 * 2];
            float4 scb = ((const float4*)scale1)[k8 * 2 + 1];
            float4 sha = ((const float4*)shift1)[k8 * 2];
            float4 shb = ((const float4*)shift1)[k8 * 2 + 1];
            float sc[8] = {sca.x, sca.y, sca.z, sca.w, scb.x, scb.y, scb.z, scb.w};
            float sh[8] = {sha.x, sha.y, sha.z, sha.w, shb.x, shb.y, shb.z, shb.w};
#pragma unroll
            for (int u = 0; u < 8; ++u)
                hv[u] = (_Float16)fmaxf(0.f, fmaf((float)y[u], sc[u], sh[u]));
        }
        *(half8*)&As[r * 136 + k8 * 8] = hv;
    }
    // stage B: W2t rows n0..n0+127
    int n0 = bn * 128;
#pragma unroll
    for (int j = 0; j < 8; ++j) {
        int i8 = t + j * 256;              // 2048 half8 = 128 n x 16
        int nn = i8 >> 4, k8 = i8 & 15;
        *(half8*)&Bs[nn * 136 + k8 * 8] = *(const half8*)&W2t[(size_t)(n0 + nn) * 128 + k8 * 8];
    }
    __syncthreads();
    int w = t >> 6, lane = t & 63;
    int quad = lane >> 4, l16 = lane & 15;
    int mwave = (w >> 1) * 64, nwave = (w & 1) * 64;
    float4v acc[4][4] = {};   // [mt][nt]
#pragma unroll
    for (int kc = 0; kc < 4; ++kc) {
        int koff = kc * 32 + quad * 8;
        half8 af[4], bf[4];
#pragma unroll
        for (int mt = 0; mt < 4; ++mt)
            af[mt] = *(const half8*)&As[(mwave + mt * 16 + l16) * 136 + koff];
#pragma unroll
        for (int nt = 0; nt < 4; ++nt)
            bf[nt] = *(const half8*)&Bs[(nwave + nt * 16 + l16) * 136 + koff];
#pragma unroll
        for (int mt = 0; mt < 4; ++mt)
#pragma unroll
            for (int nt = 0; nt < 4; ++nt)
                acc[mt][nt] = __builtin_amdgcn_mfma_f32_16x16x32_f16(af[mt], bf[nt], acc[mt][nt], 0, 0, 0);
    }
    // write y2 fp32 + per-lane column partials
    float s[4] = {}, q[4] = {};
    int colbase = n0 + nwave + l16;
#pragma unroll
    for (int mt = 0; mt < 4; ++mt) {
#pragma unroll
        for (int i = 0; i < 4; ++i) {
            int row = row0 + mwave + mt * 16 + quad * 4 + i;
            if (row < M) {
#pragma unroll
                for (int nt = 0; nt < 4; ++nt)
                    yout[(size_t)row * 256 + colbase + nt * 16] = acc[mt][nt][i];
            }
#pragma unroll
            for (int nt = 0; nt < 4; ++nt) {
                float a = acc[mt][nt][i];
                s[nt] += a; q[nt] += a * a;
            }
        }
    }
    __syncthreads();
    float* red = (float*)As;   // [128 cols][8 slots] sum, sq at +1024
    int slot = (w >> 1) * 4 + quad;
#pragma unroll
    for (int nt = 0; nt < 4; ++nt) {
        int c = (w & 1) * 64 + nt * 16 + l16;
        red[c * 8 + slot] = s[nt];
        red[1024 + c * 8 + slot] = q[nt];
    }
    __syncthreads();
    if (t < 128) {
        float ss = 0.f, qq = 0.f;
#pragma unroll
        for (int i = 0; i < 8; ++i) { ss += red[t * 8 + i]; qq += red[1024 + t * 8 + i]; }
        p2sum[(size_t)bm * 256 + n0 + t] = ss;
        p2sq[(size_t)bm * 256 + n0 + t] = qq;
    }
}

// ---------------- in-place BN2+ReLU on the x output region ----------------
__global__ void apply2_kernel(float4* __restrict__ x, const float* __restrict__ scale2,
                              const float* __restrict__ shift2, int n4) {
    int i = blockIdx.x * blockDim.x + threadIdx.x;
    if (i >= n4) return;
    int c4 = i & 63;
    float4 v = x[i];
    float4 sc = ((const float4*)scale2)[c4];
    float4 sh = ((const float4*)shift2)[c4];
    v.x = fmaxf(0.f, fmaf(v.x, sc.x, sh.x));
    v.y = fmaxf(0.f, fmaf(v.y, sc.y, sh.y));
    v.z = fmaxf(0.f, fmaf(v.z, sc.z, sh.z));
    v.w = fmaxf(0.f, fmaf(v.w, sc.w, sh.w));
    x[i] = v;
}

extern "C" void kernel_launch(void* const* d_in, const int* in_sizes, int n_in,
                              void* d_out, int out_size, void* d_ws, size_t ws_size,
                              hipStream_t stream) {
    const float* bxyz  = (const float*)d_in[0];
    const float* feat  = (const float*)d_in[1];
    const int*   sidx  = (const int*)d_in[2];
    const int*   e_point = (const int*)d_in[3];
    const int*   e_new = (const int*)d_in[4];
    const float* W0    = (const float*)d_in[5];
    const float* b0    = (const float*)d_in[6];
    const float* W1    = (const float*)d_in[7];
    const float* g1    = (const float*)d_in[9];
    const float* beta1 = (const float*)d_in[10];
    const float* W2    = (const float*)d_in[11];
    const float* g2    = (const float*)d_in[13];
    const float* beta2 = (const float*)d_in[14];
    int N = in_sizes[0] / 4;     // 400000
    int M = in_sizes[2];         // 100000
    int E = in_sizes[3];         // 3200000

    float* out0 = (float*)d_out;                       // new_bxyz [M,4]
    float* out1 = (float*)d_out + (size_t)M * 4;       // x [M,256]

    float* ws = (float*)d_ws;
    size_t o = 0;
    float* agg = ws + o; o += (size_t)M * 64;
    _Float16* y1h = (_Float16*)(ws + o); o += (size_t)M * 64;   // f16 [M,128]
    _Float16* GDh = (_Float16*)(ws + o); o += (size_t)N * 32;   // f16 [N,64]
    _Float16* W0t = (_Float16*)(ws + o); o += 2048;
    _Float16* W1t = (_Float16*)(ws + o); o += 4096;
    _Float16* W2t = (_Float16*)(ws + o); o += 16384;
    int nblk1 = (M + 127) / 128;
    int nblk2m = (M + 127) / 128;
    int nbn = 2;
    float* p1sum = ws + o; o += (size_t)nblk1 * 128;
    float* p1sq  = ws + o; o += (size_t)nblk1 * 128;
    float* p2sum = ws + o; o += (size_t)nblk2m * 256;
    float* p2sq  = ws + o; o += (size_t)nblk2m * 256;
    float* scale1 = ws + o; o += 128;
    float* shift1 = ws + o; o += 128;
    float* scale2 = ws + o; o += 256;
    float* shift2 = ws + o; o += 256;

    hipMemsetAsync(agg, 0, (size_t)M * 64 * sizeof(float), stream);
    gather_kernel<<<(M + 255) / 256, 256, 0, stream>>>((const float4*)bxyz, sidx, (float4*)out0, M);
    prep_kernel<<<176, 256, 0, stream>>>(W0, W1, W2, W0t, W1t, W2t);
    point_kernel<<<(N + 127) / 128, 256, 0, stream>>>(feat, (const float4*)bxyz, W0t, b0, GDh, N);
    int nwaves = (E + ECHUNK - 1) / ECHUNK;
    edge_kernel<<<(nwaves + 3) / 4, 256, 0, stream>>>((const float4*)out0, e_point, e_new,
                                                      GDh, W0, agg, E);
    gemm1_kernel<<<nblk1, 256, 0, stream>>>(agg, W1t, y1h, p1sum, p1sq, M);
    stats_kernel<<<128, 256, 0, stream>>>(p1sum, p1sq, g1, beta1, scale1, shift1, nblk1, 128, 1.f / M);
    gemm2_kernel<<<nblk2m * nbn, 256, 0, stream>>>(y1h, W2t, scale1, shift1, out1, p2sum, p2sq, M, nbn);
    stats_kernel<<<256, 256, 0, stream>>>(p2sum, p2sq, g2, beta2, scale2, shift2, nblk2m, 256, 1.f / M);
    apply2_kernel<<<((M * 64) + 255) / 256, 256, 0, stream>>>((float4*)out1, scale2, shift2, M * 64);
}